// Round 9
// baseline (84.598 us; speedup 1.0000x reference)
//
#include <hip/hip_runtime.h>

// Problem constants
#define DMODEL 256
#define HEADS 8
#define DHEAD 32
#define NSEQ 2048
#define BATCH 4
#define MTOT (BATCH*NSEQ)   // 8192

typedef __bf16 bf16x8 __attribute__((ext_vector_type(8)));
typedef float f32x4 __attribute__((ext_vector_type(4)));

// scale * log2(e): softmax_e(s/sqrt(32)) == softmax_2(s * CS)
#define CS 0.25507282111989365f

__device__ __forceinline__ unsigned short f2bf(float f) {
    union { float f; unsigned int u; } v; v.f = f;
    unsigned int u = v.u;
    unsigned int r = u + 0x7FFFu + ((u >> 16) & 1u);   // RNE
    return (unsigned short)(r >> 16);
}

__device__ __forceinline__ unsigned pkbf(float a, float b) {
    union { __bf16 h[2]; unsigned u; } t;
    t.h[0] = (__bf16)a; t.h[1] = (__bf16)b;
    return t.u;
}

__device__ __forceinline__ f32x4 mfma16(bf16x8 a, bf16x8 b, f32x4 c) {
    return __builtin_amdgcn_mfma_f32_16x16x32_bf16(a, b, c, 0, 0, 0);
}

#define GLD16(g, l) __builtin_amdgcn_global_load_lds( \
    (const __attribute__((address_space(1))) unsigned int*)(g), \
    (__attribute__((address_space(3))) unsigned int*)(l), 16, 0, 0)

// ---------------------------------------------------------------------------
// prep v2 (342 blocks):
//  blocks 0..79   : tiled-coalesced weight transpose -> Wt[n][k] bf16
//  blocks 80..336 : Woc = Wo@Wc fold (row 256 = boc = bo@Wc + bc)
//  blocks 337..341: bias concat
// ---------------------------------------------------------------------------
__global__ __launch_bounds__(256) void prep_kernel(
    const float* __restrict__ Wq, const float* __restrict__ Wk,
    const float* __restrict__ Wv, const float* __restrict__ Wo,
    const float* __restrict__ Wc,
    const float* __restrict__ bq, const float* __restrict__ bk,
    const float* __restrict__ bv, const float* __restrict__ bo,
    const float* __restrict__ bc,
    unsigned short* __restrict__ Wt,    // [1280][256]
    float* __restrict__ bcat,           // [1280]
    unsigned short* __restrict__ Woct,  // [256][256] = Woc^T bf16
    float* __restrict__ bocf)           // [256]
{
    const int tid = threadIdx.x;
    if (blockIdx.x < 80) {              // transpose: 64n x 64k tile
        __shared__ unsigned short Lt[64 * 72];
        const int wid = tid >> 6, lane = tid & 63;
        const int n0 = (blockIdx.x >> 2) * 64, k0 = (blockIdx.x & 3) * 64;
        const float* Wsrc; int col0;
        if (n0 < 256)       { Wsrc = Wq; col0 = n0; }
        else if (n0 < 512)  { Wsrc = Wk; col0 = n0 - 256; }
        else if (n0 < 768)  { Wsrc = Wv; col0 = n0 - 512; }
        else if (n0 < 1024) { Wsrc = Wo; col0 = n0 - 768; }
        else                { Wsrc = Wc; col0 = n0 - 1024; }
#pragma unroll
        for (int r = 0; r < 16; ++r) {
            int k = k0 + wid * 16 + r;
            Lt[lane * 72 + wid * 16 + r] = f2bf(Wsrc[k * 256 + col0 + lane]);
        }
        __syncthreads();
#pragma unroll
        for (int c = tid; c < 512; c += 256) {
            int row = c >> 3, seg = c & 7;
            *reinterpret_cast<bf16x8*>(Wt + (n0 + row) * 256 + k0 + seg * 8) =
                *reinterpret_cast<const bf16x8*>(Lt + row * 72 + seg * 8);
        }
        return;
    }
    if (blockIdx.x < 337) {             // Woc / boc fold
        int k = blockIdx.x - 80;        // 0..256
        int n = tid;                    // 0..255
        const float* arow = (k < 256) ? (Wo + k * 256) : bo;
        float a0 = 0.f, a1 = 0.f, a2 = 0.f, a3 = 0.f;
#pragma unroll 4
        for (int j = 0; j < 256; j += 4) {
            a0 = fmaf(arow[j],     Wc[j * 256 + n],       a0);
            a1 = fmaf(arow[j + 1], Wc[(j + 1) * 256 + n], a1);
            a2 = fmaf(arow[j + 2], Wc[(j + 2) * 256 + n], a2);
            a3 = fmaf(arow[j + 3], Wc[(j + 3) * 256 + n], a3);
        }
        float acc = (a0 + a1) + (a2 + a3);
        if (k < 256) Woct[n * 256 + k] = f2bf(acc);
        else         bocf[n] = acc + bc[n];
        return;
    }
    int t = (blockIdx.x - 337) * 256 + tid;   // bias concat
    if (t < 1280) {
        float v;
        if (t < 256)       v = bq[t];
        else if (t < 512)  v = bk[t - 256];
        else if (t < 768)  v = bv[t - 512];
        else if (t < 1024) v = bo[t - 768];
        else               v = bc[t - 1024];
        bcat[t] = v;
    }
}

// ---------------------------------------------------------------------------
// gemm_qkv: QKV projection from fp32 x directly (inline cvt to bf16 frags).
// Wt staged in LDS (XOR-swizzled via pre-swizzled global_load_lds source).
// 32 rows x 64 cols / wave. LDS-bounce epilogue (all stores b128):
//   type 0/1 (Q/K): [128 m][72]; Q pre-scaled by CS. type 2 (V): [64 gc][136].
// ---------------------------------------------------------------------------
__global__ __launch_bounds__(256) void gemm_qkv(
    const float* __restrict__ X,
    const unsigned short* __restrict__ Wt,
    const float* __restrict__ bias,
    unsigned short* __restrict__ outQ,
    unsigned short* __restrict__ outK,
    unsigned short* __restrict__ outVt)
{
    __shared__ __align__(16) unsigned short Bl[64 * 256];   // 32 KB
    const int tid = threadIdx.x;
    const int wid = tid >> 6;
    const int lane = tid & 63;
    const int lo = lane & 15, hi = lane >> 4;
    const int m0 = blockIdx.x * 128 + wid * 32;
    const int n0 = blockIdx.y * 64;

#pragma unroll
    for (int j = 0; j < 8; ++j) {
        int chunkbase = (j * 4 + wid) * 64;
        int chunk = chunkbase + lane;
        int row = chunk >> 5, Jp = chunk & 31;
        int J = (Jp & 24) | ((Jp ^ row) & 7);
        GLD16(Wt + (n0 + row) * 256 + J * 8, Bl + chunkbase * 8);
    }
    asm volatile("s_waitcnt vmcnt(0)" ::: "memory");
    __syncthreads();

    const float* arow0 = X + (m0 + lo) * 256 + hi * 8;
    f32x4 acc[2][4] = {};
#pragma unroll
    for (int s = 0; s < 8; ++s) {
        float4 xa = *reinterpret_cast<const float4*>(arow0 + s * 32);
        float4 xb = *reinterpret_cast<const float4*>(arow0 + s * 32 + 4);
        float4 ya = *reinterpret_cast<const float4*>(arow0 + 16 * 256 + s * 32);
        float4 yb = *reinterpret_cast<const float4*>(arow0 + 16 * 256 + s * 32 + 4);
        union { unsigned u[4]; bf16x8 v; } a0, a1;
        a0.u[0] = pkbf(xa.x, xa.y); a0.u[1] = pkbf(xa.z, xa.w);
        a0.u[2] = pkbf(xb.x, xb.y); a0.u[3] = pkbf(xb.z, xb.w);
        a1.u[0] = pkbf(ya.x, ya.y); a1.u[1] = pkbf(ya.z, ya.w);
        a1.u[2] = pkbf(yb.x, yb.y); a1.u[3] = pkbf(yb.z, yb.w);
        int Jp = ((s >> 1) << 3) | ((((s & 1) << 2) + hi) ^ (lo & 7));
#pragma unroll
        for (int n = 0; n < 4; ++n) {
            bf16x8 b = *reinterpret_cast<const bf16x8*>(
                Bl + (n * 16 + lo) * 256 + Jp * 8);
            acc[0][n] = mfma16(a0.v, b, acc[0][n]);
            acc[1][n] = mfma16(a1.v, b, acc[1][n]);
        }
    }

    // LDS-bounce epilogue
    const int type = blockIdx.y >> 2;     // 0:Q 1:K 2:V
    const int m0b = blockIdx.x * 128;
    unsigned short* Lb = Bl;
    __syncthreads();
    if (type < 2) {                       // [128][72]
#pragma unroll
        for (int mf = 0; mf < 2; ++mf)
#pragma unroll
        for (int n = 0; n < 4; ++n) {
            float bs = bias[n0 + n * 16 + lo];
#pragma unroll
            for (int i = 0; i < 4; ++i) {
                float val = acc[mf][n][i] + bs;
                if (type == 0) val *= CS;
                Lb[(wid * 32 + mf * 16 + hi * 4 + i) * 72 + n * 16 + lo] = f2bf(val);
            }
        }
    } else {                              // transposed [64][136]
#pragma unroll
        for (int mf = 0; mf < 2; ++mf)
#pragma unroll
        for (int n = 0; n < 4; ++n) {
            float bs = bias[n0 + n * 16 + lo];
            uint2 pk;
            pk.x = pkbf(acc[mf][n][0] + bs, acc[mf][n][1] + bs);
            pk.y = pkbf(acc[mf][n][2] + bs, acc[mf][n][3] + bs);
            *reinterpret_cast<uint2*>(
                Lb + (n * 16 + lo) * 136 + wid * 32 + mf * 16 + hi * 4) = pk;
        }
    }
    __syncthreads();
    if (type < 2) {
        unsigned short* outP = (type == 0) ? outQ : outK;
#pragma unroll
        for (int r = 0; r < 4; ++r) {
            int cid = r * 256 + tid;
            int m_l = cid >> 3, seg = cid & 7;
            bf16x8 chunk = *reinterpret_cast<const bf16x8*>(Lb + m_l * 72 + seg * 8);
            int m = m0b + m_l, gc = n0 + seg * 8;
            int b = m >> 11, nn = m & 2047, hh = (gc >> 5) & 7, dh = gc & 31;
            *reinterpret_cast<bf16x8*>(
                outP + (((b * 8) + hh) * 2048 + nn) * 32 + dh) = chunk;
        }
    } else {
#pragma unroll
        for (int r = 0; r < 4; ++r) {
            int cid = r * 256 + tid;
            int gcl = cid >> 4, seg = cid & 15;
            bf16x8 chunk = *reinterpret_cast<const bf16x8*>(Lb + gcl * 136 + seg * 8);
            int gc = n0 + gcl, m = m0b + seg * 8;
            int b = m >> 11, nn = m & 2047, hh = (gc >> 5) & 7, dh = gc & 31;
            *reinterpret_cast<bf16x8*>(
                outVt + (((b * 8) + hh) * 32 + dh) * 2048 + nn) = chunk;
        }
    }
}

// ---------------------------------------------------------------------------
// Flash attention v6: 1024 blocks x 256 threads (4 waves x 32 q = 128 q;
// ONE KV-half per block -> 4 independent barrier domains per CU, 32 KB LDS).
// 128-key tiles double-buffered; no-max softmax; P in-register (permlane);
// denom via ones-MFMA. Writes fp32 partials (O, d); combine in gemm_out.
// ---------------------------------------------------------------------------
__global__ __launch_bounds__(256, 4) void attn_kernel(
    const unsigned short* __restrict__ Q,    // [32][2048][32] bf16 (pre-scaled)
    const unsigned short* __restrict__ K,    // [32][2048][32] bf16
    const unsigned short* __restrict__ Vt,   // [32][32][2048] bf16
    float* __restrict__ Op,                  // [2][8192][256] f32 partial O
    float* __restrict__ dp)                  // [2][32][2048]  f32 partial denom
{
    __shared__ __align__(16) char smem[32768];   // K: [2 buf][8KB], V at +16384

    const int tid = threadIdx.x;
    const int wid = tid >> 6;          // q sub-tile 0..3
    const int lane = tid & 63;
    const int lo = lane & 15, hi = lane >> 4;

    // decode: bid = 8*(qt + 16*half + 32*g) + r ; bh = g*8+r
    const int bid = blockIdx.x;
    const int r = bid & 7, tq = bid >> 3;
    const int qt = tq & 15, half = (tq >> 4) & 1, g = tq >> 5;
    const int bh = g * 8 + r;
    const int q0 = qt * 128 + wid * 32;

    const unsigned short* Qb = Q + bh * (NSEQ * 32);
    const unsigned short* Kb = K + bh * (NSEQ * 32);
    const unsigned short* Vb = Vt + bh * (32 * NSEQ);

    bf16x8 qfA = *reinterpret_cast<const bf16x8*>(Qb + (q0 + lo) * 32 + hi * 8);
    bf16x8 qfB = *reinterpret_cast<const bf16x8*>(Qb + (q0 + 16 + lo) * 32 + hi * 8);

    const int lt = tid;
    const int kb0 = half * 1024;
    const unsigned short* ksrc0 = Kb + (kb0 + 2 * (lt >> 3) + ((lt >> 2) & 1)) * 32
                                     + ((lt & 3) ^ ((lt >> 3) & 3)) * 8;
    const unsigned short* ksrc1 = ksrc0 + 64 * 32;
    const unsigned short* vsrc0 = Vb + (lt >> 3) * NSEQ + kb0
                                     + ((lt & 7) ^ ((lt >> 3) & 7)) * 8;
    const unsigned short* vsrc1 = vsrc0 + 64;
    char* kdst = smem + lt * 16;
    char* vdst = smem + 16384 + lt * 16;

    f32x4 o0A = {}, o1A = {}, odA = {};
    f32x4 o0B = {}, o1B = {}, odB = {};
    const f32x4 z = {};
    const int prs = lo & 7;
    const int kxor = (hi ^ ((lo >> 1) & 3)) * 8;

    union { unsigned u[4]; bf16x8 v; } ones;
    ones.u[0] = 0x3F803F80u; ones.u[1] = 0x3F803F80u;
    ones.u[2] = 0x3F803F80u; ones.u[3] = 0x3F803F80u;

#define STAGE_T(tt, buf) do { \
    GLD16(ksrc0 + (tt) * 4096, kdst + (buf) * 8192); \
    GLD16(ksrc1 + (tt) * 4096, kdst + (buf) * 8192 + 4096); \
    GLD16(vsrc0 + (tt) * 128,  vdst + (buf) * 8192); \
    GLD16(vsrc1 + (tt) * 128,  vdst + (buf) * 8192 + 4096); \
} while (0)

    STAGE_T(0, 0);
    asm volatile("s_waitcnt vmcnt(0)" ::: "memory");
    __builtin_amdgcn_s_barrier();
    __builtin_amdgcn_sched_barrier(0);

    int cur = 0;
    for (int t = 0; t < 8; ++t) {
        if (t < 7) STAGE_T(t + 1, cur ^ 1);
        const unsigned short* Kc = (const unsigned short*)(smem + cur * 8192);
        const unsigned short* Vc = (const unsigned short*)(smem + 16384 + cur * 8192);

        __builtin_amdgcn_s_setprio(1);
#pragma unroll
        for (int h2 = 0; h2 < 2; ++h2) {     // 64-key sub-tiles
            const unsigned short* Kh = Kc + h2 * 2048;
            const unsigned short* Vh = Vc + h2 * 2048;
            f32x4 sA[4], sB[4];
#pragma unroll
            for (int c = 0; c < 4; ++c) {
                bf16x8 kf = *reinterpret_cast<const bf16x8*>(
                    Kh + (c * 16 + lo) * 32 + kxor);
                sA[c] = mfma16(kf, qfA, z);
                sB[c] = mfma16(kf, qfB, z);
            }
#pragma unroll
            for (int kk = 0; kk < 2; ++kk) {
                unsigned uA = pkbf(__builtin_amdgcn_exp2f(sA[2 * kk][0]),
                                   __builtin_amdgcn_exp2f(sA[2 * kk][1]));
                unsigned uB = pkbf(__builtin_amdgcn_exp2f(sA[2 * kk][2]),
                                   __builtin_amdgcn_exp2f(sA[2 * kk][3]));
                unsigned uC = pkbf(__builtin_amdgcn_exp2f(sA[2 * kk + 1][0]),
                                   __builtin_amdgcn_exp2f(sA[2 * kk + 1][1]));
                unsigned uD = pkbf(__builtin_amdgcn_exp2f(sA[2 * kk + 1][2]),
                                   __builtin_amdgcn_exp2f(sA[2 * kk + 1][3]));
                auto r1 = __builtin_amdgcn_permlane32_swap(uA, uC, false, false);
                auto r2 = __builtin_amdgcn_permlane16_swap(r1[0], r1[1], false, false);
                auto r3 = __builtin_amdgcn_permlane32_swap(uB, uD, false, false);
                auto r4 = __builtin_amdgcn_permlane16_swap(r3[0], r3[1], false, false);
                union { unsigned u[4]; bf16x8 v; } pbA;
                pbA.u[0] = r2[0]; pbA.u[1] = r4[0]; pbA.u[2] = r2[1]; pbA.u[3] = r4[1];

                unsigned wA = pkbf(__builtin_amdgcn_exp2f(sB[2 * kk][0]),
                                   __builtin_amdgcn_exp2f(sB[2 * kk][1]));
                unsigned wB = pkbf(__builtin_amdgcn_exp2f(sB[2 * kk][2]),
                                   __builtin_amdgcn_exp2f(sB[2 * kk][3]));
                unsigned wC = pkbf(__builtin_amdgcn_exp2f(sB[2 * kk + 1][0]),
                                   __builtin_amdgcn_exp2f(sB[2 * kk + 1][1]));
                unsigned wD = pkbf(__builtin_amdgcn_exp2f(sB[2 * kk + 1][2]),
                                   __builtin_amdgcn_exp2f(sB[2 * kk + 1][3]));
                auto t1 = __builtin_amdgcn_permlane32_swap(wA, wC, false, false);
                auto t2 = __builtin_amdgcn_permlane16_swap(t1[0], t1[1], false, false);
                auto t3 = __builtin_amdgcn_permlane32_swap(wB, wD, false, false);
                auto t4 = __builtin_amdgcn_permlane16_swap(t3[0], t3[1], false, false);
                union { unsigned u[4]; bf16x8 v; } pbB;
                pbB.u[0] = t2[0]; pbB.u[1] = t4[0]; pbB.u[2] = t2[1]; pbB.u[3] = t4[1];

                int sw = ((4 * kk + hi) ^ prs) * 8;
                bf16x8 a0 = *reinterpret_cast<const bf16x8*>(Vh + lo * 64 + sw);
                bf16x8 a1 = *reinterpret_cast<const bf16x8*>(Vh + (16 + lo) * 64 + sw);
                o0A = mfma16(a0, pbA.v, o0A);
                o1A = mfma16(a1, pbA.v, o1A);
                odA = mfma16(ones.v, pbA.v, odA);
                o0B = mfma16(a0, pbB.v, o0B);
                o1B = mfma16(a1, pbB.v, o1B);
                odB = mfma16(ones.v, pbB.v, odB);
            }
        }
        __builtin_amdgcn_s_setprio(0);

        if (t < 7) {
            asm volatile("s_waitcnt vmcnt(0)" ::: "memory");
            __builtin_amdgcn_s_barrier();
            __builtin_amdgcn_sched_barrier(0);
            cur ^= 1;
        }
    }

    // write fp32 partials (lane holds O^T[dh=4hi+i][q=lo])
    const int b = bh >> 3, h = bh & 7;
    float* OpH = Op + (size_t)half * 2097152
                    + (size_t)(b * 2048 + q0 + lo) * 256 + h * 32;
    *reinterpret_cast<f32x4*>(OpH + hi * 4)             = o0A;
    *reinterpret_cast<f32x4*>(OpH + 16 + hi * 4)        = o1A;
    *reinterpret_cast<f32x4*>(OpH + 16 * 256 + hi * 4)      = o0B;
    *reinterpret_cast<f32x4*>(OpH + 16 * 256 + 16 + hi * 4) = o1B;
    if (hi == 0) {
        float* dpH = dp + half * 65536 + bh * 2048 + q0;
        dpH[lo]      = odA[0];
        dpH[16 + lo] = odB[0];
    }
#undef STAGE_T
}

// ---------------------------------------------------------------------------
// gemm_out: out = x + ((Op0+Op1)/d) @ Woc + boc. A-frags built inline from
// fp32 partials (head = s exactly, one denom per frag). B = Woct staged in
// LDS (swizzled). 32 rows x 64 cols / wave.
// ---------------------------------------------------------------------------
__global__ __launch_bounds__(256) void gemm_out(
    const float* __restrict__ Op,       // [2][8192][256]
    const float* __restrict__ dp,       // [2][32][2048]
    const unsigned short* __restrict__ Wt,    // Woct
    const float* __restrict__ boc,
    const float* __restrict__ xres,
    float* __restrict__ outF)
{
    __shared__ __align__(16) unsigned short Bl[64 * 256];   // 32 KB
    const int tid = threadIdx.x;
    const int wid = tid >> 6;
    const int lane = tid & 63;
    const int lo = lane & 15, hi = lane >> 4;
    const int m0 = blockIdx.x * 128 + wid * 32;
    const int n0 = blockIdx.y * 64;

#pragma unroll
    for (int j = 0; j < 8; ++j) {
        int chunkbase = (j * 4 + wid) * 64;
        int chunk = chunkbase + lane;
        int row = chunk >> 5, Jp = chunk & 31;
        int J = (Jp & 24) | ((Jp ^ row) & 7);
        GLD16(Wt + (n0 + row) * 256 + J * 8, Bl + chunkbase * 8);
    }
    asm volatile("s_waitcnt vmcnt(0)" ::: "memory");
    __syncthreads();

    const int mA = m0 + lo;
    const float* op0 = Op + (size_t)mA * 256 + hi * 8;            // half 0, mf 0
    const int b0 = mA >> 11, nn0 = mA & 2047;
    const int b1 = (mA + 16) >> 11, nn1 = (mA + 16) & 2047;
    const float* db0 = dp + b0 * 16384 + nn0;
    const float* db1 = dp + b1 * 16384 + nn1;

    f32x4 acc[2][4] = {};
#pragma unroll
    for (int s = 0; s < 8; ++s) {
        float d0 = db0[s * 2048] + db0[65536 + s * 2048];
        float d1 = db1[s * 2048] + db1[65536 + s * 2048];
        float i0 = 1.0f / d0, i1 = 1.0f / d1;
        f32x4 pa = *reinterpret_cast<const f32x4*>(op0 + s * 32);
        f32x4 pb = *reinterpret_cast<const f32x4*>(op0 + s * 32 + 4);
        f32x4 qa = *reinterpret_cast<const f32x4*>(op0 + 2097152 + s * 32);
        f32x4 qb = *reinterpret_cast<const f32x4*>(op0 + 2097152 + s * 32 + 4);
        f32x4 ra = *reinterpret_cast<const f32x4*>(op0 + 16 * 256 + s * 32);
        f32x4 rb = *reinterpret_cast<const f32x4*>(op0 + 16 * 256 + s * 32 + 4);
        f32x4 sa = *reinterpret_cast<const f32x4*>(op0 + 2097152 + 16 * 256 + s * 32);
        f32x4 sb = *reinterpret_cast<const f32x4*>(op0 + 2097152 + 16 * 256 + s * 32 + 4);
        union { unsigned u[4]; bf16x8 v; } a0, a1;
        a0.u[0] = pkbf((pa[0] + qa[0]) * i0, (pa[1] + qa[1]) * i0);
        a0.u[1] = pkbf((pa[2] + qa[2]) * i0, (pa[3] + qa[3]) * i0);
        a0.u[2] = pkbf((pb[0] + qb[0]) * i0, (pb[1] + qb[1]) * i0);
        a0.u[3] = pkbf((pb[2] + qb[2]) * i0, (pb[3] + qb[3]) * i0);
        a1.u[0] = pkbf((ra[0] + sa[0]) * i1, (ra[1] + sa[1]) * i1);
        a1.u[1] = pkbf((ra[2] + sa[2]) * i1, (ra[3] + sa[3]) * i1);
        a1.u[2] = pkbf((rb[0] + sb[0]) * i1, (rb[1] + sb[1]) * i1);
        a1.u[3] = pkbf((rb[2] + sb[2]) * i1, (rb[3] + sb[3]) * i1);
        int Jp = ((s >> 1) << 3) | ((((s & 1) << 2) + hi) ^ (lo & 7));
#pragma unroll
        for (int n = 0; n < 4; ++n) {
            bf16x8 bfr = *reinterpret_cast<const bf16x8*>(
                Bl + (n * 16 + lo) * 256 + Jp * 8);
            acc[0][n] = mfma16(a0.v, bfr, acc[0][n]);
            acc[1][n] = mfma16(a1.v, bfr, acc[1][n]);
        }
    }
#pragma unroll
    for (int mf = 0; mf < 2; ++mf) {
        const int row_base = m0 + mf * 16 + hi * 4;
#pragma unroll
        for (int n = 0; n < 4; ++n) {
            int gc = n0 + n * 16 + lo;
            float bs = boc[gc];
#pragma unroll
            for (int i = 0; i < 4; ++i)
                outF[(row_base + i) * 256 + gc] =
                    xres[(row_base + i) * 256 + gc] + acc[mf][n][i] + bs;
        }
    }
}

// ---------------------------------------------------------------------------
extern "C" void kernel_launch(void* const* d_in, const int* in_sizes, int n_in,
                              void* d_out, int out_size, void* d_ws, size_t ws_size,
                              hipStream_t stream) {
    const float* x  = (const float*)d_in[0];
    const float* Wq = (const float*)d_in[1];
    const float* bq = (const float*)d_in[2];
    const float* Wk = (const float*)d_in[3];
    const float* bk = (const float*)d_in[4];
    const float* Wv = (const float*)d_in[5];
    const float* bv = (const float*)d_in[6];
    const float* Wo = (const float*)d_in[7];
    const float* bo = (const float*)d_in[8];
    const float* Wc = (const float*)d_in[9];
    const float* bc = (const float*)d_in[10];
    float* out = (float*)d_out;

    char* p = (char*)d_ws;
    unsigned short* Wt   = (unsigned short*)p;  p += (size_t)1280 * 256 * 2;      // 640 KB
    float* bcat          = (float*)p;           p += (size_t)1280 * 4;            // 5 KB
    unsigned short* Qw   = (unsigned short*)p;  p += (size_t)32 * 2048 * 32 * 2;  // 4 MB
    unsigned short* Kw   = (unsigned short*)p;  p += (size_t)32 * 2048 * 32 * 2;  // 4 MB
    unsigned short* Vtw  = (unsigned short*)p;  p += (size_t)32 * 32 * 2048 * 2;  // 4 MB
    float* Opart         = (float*)p;           p += (size_t)2 * MTOT * 256 * 4;  // 16 MB
    float* dpart         = (float*)p;           p += (size_t)2 * 32 * 2048 * 4;   // 512 KB
    unsigned short* Woct = (unsigned short*)p;  p += (size_t)256 * 256 * 2;       // 128 KB
    float* bocf          = (float*)p;           p += (size_t)256 * 4;             // 1 KB

    // prep: 80 transpose + 257 fold + 5 bias = 342 blocks
    prep_kernel<<<342, 256, 0, stream>>>(Wq, Wk, Wv, Wo, Wc,
                                         bq, bk, bv, bo, bc,
                                         Wt, bcat, Woct, bocf);
    // QKV projection (reads fp32 x directly)
    gemm_qkv<<<dim3(64, 12), 256, 0, stream>>>(x, Wt, bcat, Qw, Kw, Vtw);
    // attention (fp32 partials)
    attn_kernel<<<1024, 256, 0, stream>>>(Qw, Kw, Vtw, Opart, dpart);
    // fused output+context projection + residual + partial combine
    gemm_out<<<dim3(64, 4), 256, 0, stream>>>(Opart, dpart, Woct, bocf, x, out);
}

// Round 10
// 67.864 us; speedup vs baseline: 1.2466x; 1.2466x over previous
//
#include <hip/hip_runtime.h>

// Problem constants
#define DMODEL 256
#define HEADS 8
#define DHEAD 32
#define NSEQ 2048
#define BATCH 4
#define MTOT (BATCH*NSEQ)   // 8192

typedef __bf16 bf16x8 __attribute__((ext_vector_type(8)));
typedef float f32x4 __attribute__((ext_vector_type(4)));

// scale * log2(e): softmax_e(s/sqrt(32)) == softmax_2(s * CS)
#define CS 0.25507282111989365f

__device__ __forceinline__ unsigned short f2bf(float f) {
    union { float f; unsigned int u; } v; v.f = f;
    unsigned int u = v.u;
    unsigned int r = u + 0x7FFFu + ((u >> 16) & 1u);   // RNE
    return (unsigned short)(r >> 16);
}

__device__ __forceinline__ unsigned pkbf(float a, float b) {
    union { __bf16 h[2]; unsigned u; } t;
    t.h[0] = (__bf16)a; t.h[1] = (__bf16)b;
    return t.u;
}

__device__ __forceinline__ f32x4 mfma16(bf16x8 a, bf16x8 b, f32x4 c) {
    return __builtin_amdgcn_mfma_f32_16x16x32_bf16(a, b, c, 0, 0, 0);
}

#define GLD16(g, l) __builtin_amdgcn_global_load_lds( \
    (const __attribute__((address_space(1))) unsigned int*)(g), \
    (__attribute__((address_space(3))) unsigned int*)(l), 16, 0, 0)

// ---------------------------------------------------------------------------
// prep (342 blocks):
//  blocks 0..79   : tiled-coalesced weight transpose -> Wt[n][k] bf16
//  blocks 80..336 : Woc = Wo@Wc fold (row 256 = boc = bo@Wc + bc)
//  blocks 337..341: bias concat
// ---------------------------------------------------------------------------
__global__ __launch_bounds__(256) void prep_kernel(
    const float* __restrict__ Wq, const float* __restrict__ Wk,
    const float* __restrict__ Wv, const float* __restrict__ Wo,
    const float* __restrict__ Wc,
    const float* __restrict__ bq, const float* __restrict__ bk,
    const float* __restrict__ bv, const float* __restrict__ bo,
    const float* __restrict__ bc,
    unsigned short* __restrict__ Wt,    // [1280][256]
    float* __restrict__ bcat,           // [1280]
    unsigned short* __restrict__ Woct,  // [256][256] = Woc^T bf16
    float* __restrict__ bocf)           // [256]
{
    const int tid = threadIdx.x;
    if (blockIdx.x < 80) {              // transpose: 64n x 64k tile
        __shared__ unsigned short Lt[64 * 72];
        const int wid = tid >> 6, lane = tid & 63;
        const int n0 = (blockIdx.x >> 2) * 64, k0 = (blockIdx.x & 3) * 64;
        const float* Wsrc; int col0;
        if (n0 < 256)       { Wsrc = Wq; col0 = n0; }
        else if (n0 < 512)  { Wsrc = Wk; col0 = n0 - 256; }
        else if (n0 < 768)  { Wsrc = Wv; col0 = n0 - 512; }
        else if (n0 < 1024) { Wsrc = Wo; col0 = n0 - 768; }
        else                { Wsrc = Wc; col0 = n0 - 1024; }
#pragma unroll
        for (int r = 0; r < 16; ++r) {
            int k = k0 + wid * 16 + r;
            Lt[lane * 72 + wid * 16 + r] = f2bf(Wsrc[k * 256 + col0 + lane]);
        }
        __syncthreads();
#pragma unroll
        for (int c = tid; c < 512; c += 256) {
            int row = c >> 3, seg = c & 7;
            *reinterpret_cast<bf16x8*>(Wt + (n0 + row) * 256 + k0 + seg * 8) =
                *reinterpret_cast<const bf16x8*>(Lt + row * 72 + seg * 8);
        }
        return;
    }
    if (blockIdx.x < 337) {             // Woc / boc fold
        int k = blockIdx.x - 80;        // 0..256
        int n = tid;                    // 0..255
        const float* arow = (k < 256) ? (Wo + k * 256) : bo;
        float a0 = 0.f, a1 = 0.f, a2 = 0.f, a3 = 0.f;
#pragma unroll 4
        for (int j = 0; j < 256; j += 4) {
            a0 = fmaf(arow[j],     Wc[j * 256 + n],       a0);
            a1 = fmaf(arow[j + 1], Wc[(j + 1) * 256 + n], a1);
            a2 = fmaf(arow[j + 2], Wc[(j + 2) * 256 + n], a2);
            a3 = fmaf(arow[j + 3], Wc[(j + 3) * 256 + n], a3);
        }
        float acc = (a0 + a1) + (a2 + a3);
        if (k < 256) Woct[n * 256 + k] = f2bf(acc);
        else         bocf[n] = acc + bc[n];
        return;
    }
    int t = (blockIdx.x - 337) * 256 + tid;   // bias concat
    if (t < 1280) {
        float v;
        if (t < 256)       v = bq[t];
        else if (t < 512)  v = bk[t - 256];
        else if (t < 768)  v = bv[t - 512];
        else if (t < 1024) v = bo[t - 768];
        else               v = bc[t - 1024];
        bcat[t] = v;
    }
}

// ---------------------------------------------------------------------------
// gemm_qkv: QKV projection from fp32 x directly (inline cvt to bf16 frags).
// Wt staged in LDS (XOR-swizzled via pre-swizzled global_load_lds source).
// 32 rows x 64 cols / wave. LDS-bounce epilogue (all stores b128):
//   type 0/1 (Q/K): [128 m][72]; Q pre-scaled by CS. type 2 (V): [64 gc][136].
// ---------------------------------------------------------------------------
__global__ __launch_bounds__(256) void gemm_qkv(
    const float* __restrict__ X,
    const unsigned short* __restrict__ Wt,
    const float* __restrict__ bias,
    unsigned short* __restrict__ outQ,
    unsigned short* __restrict__ outK,
    unsigned short* __restrict__ outVt)
{
    __shared__ __align__(16) unsigned short Bl[64 * 256];   // 32 KB
    const int tid = threadIdx.x;
    const int wid = tid >> 6;
    const int lane = tid & 63;
    const int lo = lane & 15, hi = lane >> 4;
    const int m0 = blockIdx.x * 128 + wid * 32;
    const int n0 = blockIdx.y * 64;

#pragma unroll
    for (int j = 0; j < 8; ++j) {
        int chunkbase = (j * 4 + wid) * 64;
        int chunk = chunkbase + lane;
        int row = chunk >> 5, Jp = chunk & 31;
        int J = (Jp & 24) | ((Jp ^ row) & 7);
        GLD16(Wt + (n0 + row) * 256 + J * 8, Bl + chunkbase * 8);
    }
    asm volatile("s_waitcnt vmcnt(0)" ::: "memory");
    __syncthreads();

    const float* arow0 = X + (m0 + lo) * 256 + hi * 8;
    f32x4 acc[2][4] = {};
#pragma unroll
    for (int s = 0; s < 8; ++s) {
        float4 xa = *reinterpret_cast<const float4*>(arow0 + s * 32);
        float4 xb = *reinterpret_cast<const float4*>(arow0 + s * 32 + 4);
        float4 ya = *reinterpret_cast<const float4*>(arow0 + 16 * 256 + s * 32);
        float4 yb = *reinterpret_cast<const float4*>(arow0 + 16 * 256 + s * 32 + 4);
        union { unsigned u[4]; bf16x8 v; } a0, a1;
        a0.u[0] = pkbf(xa.x, xa.y); a0.u[1] = pkbf(xa.z, xa.w);
        a0.u[2] = pkbf(xb.x, xb.y); a0.u[3] = pkbf(xb.z, xb.w);
        a1.u[0] = pkbf(ya.x, ya.y); a1.u[1] = pkbf(ya.z, ya.w);
        a1.u[2] = pkbf(yb.x, yb.y); a1.u[3] = pkbf(yb.z, yb.w);
        int Jp = ((s >> 1) << 3) | ((((s & 1) << 2) + hi) ^ (lo & 7));
#pragma unroll
        for (int n = 0; n < 4; ++n) {
            bf16x8 b = *reinterpret_cast<const bf16x8*>(
                Bl + (n * 16 + lo) * 256 + Jp * 8);
            acc[0][n] = mfma16(a0.v, b, acc[0][n]);
            acc[1][n] = mfma16(a1.v, b, acc[1][n]);
        }
    }

    // LDS-bounce epilogue
    const int type = blockIdx.y >> 2;     // 0:Q 1:K 2:V
    const int m0b = blockIdx.x * 128;
    unsigned short* Lb = Bl;
    __syncthreads();
    if (type < 2) {                       // [128][72]
#pragma unroll
        for (int mf = 0; mf < 2; ++mf)
#pragma unroll
        for (int n = 0; n < 4; ++n) {
            float bs = bias[n0 + n * 16 + lo];
#pragma unroll
            for (int i = 0; i < 4; ++i) {
                float val = acc[mf][n][i] + bs;
                if (type == 0) val *= CS;
                Lb[(wid * 32 + mf * 16 + hi * 4 + i) * 72 + n * 16 + lo] = f2bf(val);
            }
        }
    } else {                              // transposed [64][136]
#pragma unroll
        for (int mf = 0; mf < 2; ++mf)
#pragma unroll
        for (int n = 0; n < 4; ++n) {
            float bs = bias[n0 + n * 16 + lo];
            uint2 pk;
            pk.x = pkbf(acc[mf][n][0] + bs, acc[mf][n][1] + bs);
            pk.y = pkbf(acc[mf][n][2] + bs, acc[mf][n][3] + bs);
            *reinterpret_cast<uint2*>(
                Lb + (n * 16 + lo) * 136 + wid * 32 + mf * 16 + hi * 4) = pk;
        }
    }
    __syncthreads();
    if (type < 2) {
        unsigned short* outP = (type == 0) ? outQ : outK;
#pragma unroll
        for (int r = 0; r < 4; ++r) {
            int cid = r * 256 + tid;
            int m_l = cid >> 3, seg = cid & 7;
            bf16x8 chunk = *reinterpret_cast<const bf16x8*>(Lb + m_l * 72 + seg * 8);
            int m = m0b + m_l, gc = n0 + seg * 8;
            int b = m >> 11, nn = m & 2047, hh = (gc >> 5) & 7, dh = gc & 31;
            *reinterpret_cast<bf16x8*>(
                outP + (((b * 8) + hh) * 2048 + nn) * 32 + dh) = chunk;
        }
    } else {
#pragma unroll
        for (int r = 0; r < 4; ++r) {
            int cid = r * 256 + tid;
            int gcl = cid >> 4, seg = cid & 15;
            bf16x8 chunk = *reinterpret_cast<const bf16x8*>(Lb + gcl * 136 + seg * 8);
            int gc = n0 + gcl, m = m0b + seg * 8;
            int b = m >> 11, nn = m & 2047, hh = (gc >> 5) & 7, dh = gc & 31;
            *reinterpret_cast<bf16x8*>(
                outVt + (((b * 8) + hh) * 32 + dh) * 2048 + nn) = chunk;
        }
    }
}

// ---------------------------------------------------------------------------
// Flash attention (R8 structure): 32 q-rows per wave (groups A/B share every
// K/V fragment), KVBLK=128, split-KV halves in one 512-thread block,
// double-buffered 64KB LDS, no-max softmax, P in-register (permlane),
// denom via ones-MFMA. In-block half combine via LDS; ctx out bf16.
// ---------------------------------------------------------------------------
__global__ __launch_bounds__(512, 4) void attn_kernel(
    const unsigned short* __restrict__ Q,    // [32][2048][32] bf16 (pre-scaled)
    const unsigned short* __restrict__ K,    // [32][2048][32] bf16
    const unsigned short* __restrict__ Vt,   // [32][32][2048] bf16
    unsigned short* __restrict__ ctx)        // [8192][256] bf16 (heads merged)
{
    __shared__ __align__(16) char smem[65536];

    const int tid = threadIdx.x;
    const int wid = tid >> 6;          // 0..7
    const int lane = tid & 63;
    const int lo = lane & 15, hi = lane >> 4;
    const int half = wid >> 2;
    const int qw = wid & 3;

    // XCD swizzle: 512 blocks; bid = 8*(qt + 16*g) + r ; bh = g*8+r
    const int bid = blockIdx.x;
    const int bh = ((bid >> 7) << 3) | (bid & 7);
    const int qt = (bid >> 3) & 15;
    const int q0 = qt * 128 + qw * 32;

    const unsigned short* Qb = Q + bh * (NSEQ * 32);
    const unsigned short* Kb = K + bh * (NSEQ * 32);
    const unsigned short* Vb = Vt + bh * (32 * NSEQ);

    bf16x8 qfA = *reinterpret_cast<const bf16x8*>(Qb + (q0 + lo) * 32 + hi * 8);
    bf16x8 qfB = *reinterpret_cast<const bf16x8*>(Qb + (q0 + 16 + lo) * 32 + hi * 8);

    const int lt = tid & 255;
    const int kb0 = half * 1024;
    const unsigned short* ksrc0 = Kb + (kb0 + 2 * (lt >> 3) + ((lt >> 2) & 1)) * 32
                                     + ((lt & 3) ^ ((lt >> 3) & 3)) * 8;
    const unsigned short* ksrc1 = ksrc0 + 64 * 32;
    const unsigned short* vsrc0 = Vb + (lt >> 3) * NSEQ + kb0
                                     + ((lt & 7) ^ ((lt >> 3) & 7)) * 8;
    const unsigned short* vsrc1 = vsrc0 + 64;
    char* kdst = smem + half * 16384 + lt * 16;
    char* vdst = smem + 32768 + half * 16384 + lt * 16;

    f32x4 o0A = {}, o1A = {}, odA = {};
    f32x4 o0B = {}, o1B = {}, odB = {};
    const f32x4 z = {};
    const int prs = lo & 7;
    const int kxor = (hi ^ ((lo >> 1) & 3)) * 8;

    union { unsigned u[4]; bf16x8 v; } ones;
    ones.u[0] = 0x3F803F80u; ones.u[1] = 0x3F803F80u;
    ones.u[2] = 0x3F803F80u; ones.u[3] = 0x3F803F80u;

#define STAGE_T(tt, buf) do { \
    GLD16(ksrc0 + (tt) * 4096, kdst + (buf) * 8192); \
    GLD16(ksrc1 + (tt) * 4096, kdst + (buf) * 8192 + 4096); \
    GLD16(vsrc0 + (tt) * 128,  vdst + (buf) * 8192); \
    GLD16(vsrc1 + (tt) * 128,  vdst + (buf) * 8192 + 4096); \
} while (0)

    STAGE_T(0, 0);
    asm volatile("s_waitcnt vmcnt(0)" ::: "memory");
    __builtin_amdgcn_s_barrier();
    __builtin_amdgcn_sched_barrier(0);

    int cur = 0;
    for (int t = 0; t < 8; ++t) {
        if (t < 7) STAGE_T(t + 1, cur ^ 1);
        const unsigned short* Kc =
            (const unsigned short*)(smem + half * 16384 + cur * 8192);
        const unsigned short* Vc =
            (const unsigned short*)(smem + 32768 + half * 16384 + cur * 8192);

        __builtin_amdgcn_s_setprio(1);
#pragma unroll
        for (int h2 = 0; h2 < 2; ++h2) {     // 64-key sub-tiles
            const unsigned short* Kh = Kc + h2 * 2048;
            const unsigned short* Vh = Vc + h2 * 2048;
            f32x4 sA[4], sB[4];
#pragma unroll
            for (int c = 0; c < 4; ++c) {
                bf16x8 kf = *reinterpret_cast<const bf16x8*>(
                    Kh + (c * 16 + lo) * 32 + kxor);
                sA[c] = mfma16(kf, qfA, z);
                sB[c] = mfma16(kf, qfB, z);
            }
#pragma unroll
            for (int kk = 0; kk < 2; ++kk) {
                unsigned uA = pkbf(__builtin_amdgcn_exp2f(sA[2 * kk][0]),
                                   __builtin_amdgcn_exp2f(sA[2 * kk][1]));
                unsigned uB = pkbf(__builtin_amdgcn_exp2f(sA[2 * kk][2]),
                                   __builtin_amdgcn_exp2f(sA[2 * kk][3]));
                unsigned uC = pkbf(__builtin_amdgcn_exp2f(sA[2 * kk + 1][0]),
                                   __builtin_amdgcn_exp2f(sA[2 * kk + 1][1]));
                unsigned uD = pkbf(__builtin_amdgcn_exp2f(sA[2 * kk + 1][2]),
                                   __builtin_amdgcn_exp2f(sA[2 * kk + 1][3]));
                auto r1 = __builtin_amdgcn_permlane32_swap(uA, uC, false, false);
                auto r2 = __builtin_amdgcn_permlane16_swap(r1[0], r1[1], false, false);
                auto r3 = __builtin_amdgcn_permlane32_swap(uB, uD, false, false);
                auto r4 = __builtin_amdgcn_permlane16_swap(r3[0], r3[1], false, false);
                union { unsigned u[4]; bf16x8 v; } pbA;
                pbA.u[0] = r2[0]; pbA.u[1] = r4[0]; pbA.u[2] = r2[1]; pbA.u[3] = r4[1];

                unsigned wA = pkbf(__builtin_amdgcn_exp2f(sB[2 * kk][0]),
                                   __builtin_amdgcn_exp2f(sB[2 * kk][1]));
                unsigned wB = pkbf(__builtin_amdgcn_exp2f(sB[2 * kk][2]),
                                   __builtin_amdgcn_exp2f(sB[2 * kk][3]));
                unsigned wC = pkbf(__builtin_amdgcn_exp2f(sB[2 * kk + 1][0]),
                                   __builtin_amdgcn_exp2f(sB[2 * kk + 1][1]));
                unsigned wD = pkbf(__builtin_amdgcn_exp2f(sB[2 * kk + 1][2]),
                                   __builtin_amdgcn_exp2f(sB[2 * kk + 1][3]));
                auto t1 = __builtin_amdgcn_permlane32_swap(wA, wC, false, false);
                auto t2 = __builtin_amdgcn_permlane16_swap(t1[0], t1[1], false, false);
                auto t3 = __builtin_amdgcn_permlane32_swap(wB, wD, false, false);
                auto t4 = __builtin_amdgcn_permlane16_swap(t3[0], t3[1], false, false);
                union { unsigned u[4]; bf16x8 v; } pbB;
                pbB.u[0] = t2[0]; pbB.u[1] = t4[0]; pbB.u[2] = t2[1]; pbB.u[3] = t4[1];

                int sw = ((4 * kk + hi) ^ prs) * 8;
                bf16x8 a0 = *reinterpret_cast<const bf16x8*>(Vh + lo * 64 + sw);
                bf16x8 a1 = *reinterpret_cast<const bf16x8*>(Vh + (16 + lo) * 64 + sw);
                o0A = mfma16(a0, pbA.v, o0A);
                o1A = mfma16(a1, pbA.v, o1A);
                odA = mfma16(ones.v, pbA.v, odA);
                o0B = mfma16(a0, pbB.v, o0B);
                o1B = mfma16(a1, pbB.v, o1B);
                odB = mfma16(ones.v, pbB.v, odB);
            }
        }
        __builtin_amdgcn_s_setprio(0);

        if (t < 7) {
            asm volatile("s_waitcnt vmcnt(0)" ::: "memory");
            __builtin_amdgcn_s_barrier();
            __builtin_amdgcn_sched_barrier(0);
            cur ^= 1;
        }
    }

    // combine halves (pure addition; no-max softmax partials)
    float* comb = (float*)smem;                 // [4][64][18]
    const int cidx = (qw * 64 + lane) * 18;
    __syncthreads();
    if (half) {
        *reinterpret_cast<f32x4*>(comb + cidx)      = o0A;
        *reinterpret_cast<f32x4*>(comb + cidx + 4)  = o1A;
        comb[cidx + 8] = odA[0];
        *reinterpret_cast<f32x4*>(comb + cidx + 9)  = o0B;
        *reinterpret_cast<f32x4*>(comb + cidx + 13) = o1B;
        comb[cidx + 17] = odB[0];
    }
    __syncthreads();
    if (!half) {
        o0A += *reinterpret_cast<const f32x4*>(comb + cidx);
        o1A += *reinterpret_cast<const f32x4*>(comb + cidx + 4);
        float invA = 1.0f / (odA[0] + comb[cidx + 8]);
        o0B += *reinterpret_cast<const f32x4*>(comb + cidx + 9);
        o1B += *reinterpret_cast<const f32x4*>(comb + cidx + 13);
        float invB = 1.0f / (odB[0] + comb[cidx + 17]);

        const int b = bh >> 3, h = bh & 7;
        unsigned short* dstA = ctx + (size_t)((b * 2048 + q0 + lo)) * 256 + h * 32;
        unsigned short* dstB = dstA + 16 * 256;
        ushort4 w0, w1;
        w0.x = f2bf(o0A[0] * invA); w0.y = f2bf(o0A[1] * invA);
        w0.z = f2bf(o0A[2] * invA); w0.w = f2bf(o0A[3] * invA);
        w1.x = f2bf(o1A[0] * invA); w1.y = f2bf(o1A[1] * invA);
        w1.z = f2bf(o1A[2] * invA); w1.w = f2bf(o1A[3] * invA);
        *reinterpret_cast<ushort4*>(dstA + hi * 4)      = w0;
        *reinterpret_cast<ushort4*>(dstA + 16 + hi * 4) = w1;
        w0.x = f2bf(o0B[0] * invB); w0.y = f2bf(o0B[1] * invB);
        w0.z = f2bf(o0B[2] * invB); w0.w = f2bf(o0B[3] * invB);
        w1.x = f2bf(o1B[0] * invB); w1.y = f2bf(o1B[1] * invB);
        w1.z = f2bf(o1B[2] * invB); w1.w = f2bf(o1B[3] * invB);
        *reinterpret_cast<ushort4*>(dstB + hi * 4)      = w0;
        *reinterpret_cast<ushort4*>(dstB + 16 + hi * 4) = w1;
    }
#undef STAGE_T
}

// ---------------------------------------------------------------------------
// gemm_ctx: out = x + ctx @ Woc + boc. A = ctx bf16 direct; B = Woct staged
// in LDS (swizzled). 32 rows x 64 cols / wave.
// ---------------------------------------------------------------------------
__global__ __launch_bounds__(256) void gemm_ctx(
    const unsigned short* __restrict__ A,
    const unsigned short* __restrict__ Wt,
    const float* __restrict__ boc,
    const float* __restrict__ xres,
    float* __restrict__ outF)
{
    __shared__ __align__(16) unsigned short Bl[64 * 256];   // 32 KB
    const int tid = threadIdx.x;
    const int wid = tid >> 6;
    const int lane = tid & 63;
    const int lo = lane & 15, hi = lane >> 4;
    const int m0 = blockIdx.x * 128 + wid * 32;
    const int n0 = blockIdx.y * 64;

#pragma unroll
    for (int j = 0; j < 8; ++j) {
        int chunkbase = (j * 4 + wid) * 64;
        int chunk = chunkbase + lane;
        int row = chunk >> 5, Jp = chunk & 31;
        int J = (Jp & 24) | ((Jp ^ row) & 7);
        GLD16(Wt + (n0 + row) * 256 + J * 8, Bl + chunkbase * 8);
    }
    asm volatile("s_waitcnt vmcnt(0)" ::: "memory");
    __syncthreads();

    const unsigned short* arow0 = A + (m0 + lo) * 256 + hi * 8;
    f32x4 acc[2][4] = {};
#pragma unroll
    for (int s = 0; s < 8; ++s) {
        bf16x8 a0 = *reinterpret_cast<const bf16x8*>(arow0 + s * 32);
        bf16x8 a1 = *reinterpret_cast<const bf16x8*>(arow0 + 16 * 256 + s * 32);
        int Jp = ((s >> 1) << 3) | ((((s & 1) << 2) + hi) ^ (lo & 7));
#pragma unroll
        for (int n = 0; n < 4; ++n) {
            bf16x8 b = *reinterpret_cast<const bf16x8*>(
                Bl + (n * 16 + lo) * 256 + Jp * 8);
            acc[0][n] = mfma16(a0, b, acc[0][n]);
            acc[1][n] = mfma16(a1, b, acc[1][n]);
        }
    }
#pragma unroll
    for (int mf = 0; mf < 2; ++mf) {
        const int row_base = m0 + mf * 16 + hi * 4;
#pragma unroll
        for (int n = 0; n < 4; ++n) {
            int gc = n0 + n * 16 + lo;
            float bs = boc[gc];
#pragma unroll
            for (int i = 0; i < 4; ++i)
                outF[(row_base + i) * 256 + gc] =
                    xres[(row_base + i) * 256 + gc] + acc[mf][n][i] + bs;
        }
    }
}

// ---------------------------------------------------------------------------
extern "C" void kernel_launch(void* const* d_in, const int* in_sizes, int n_in,
                              void* d_out, int out_size, void* d_ws, size_t ws_size,
                              hipStream_t stream) {
    const float* x  = (const float*)d_in[0];
    const float* Wq = (const float*)d_in[1];
    const float* bq = (const float*)d_in[2];
    const float* Wk = (const float*)d_in[3];
    const float* bk = (const float*)d_in[4];
    const float* Wv = (const float*)d_in[5];
    const float* bv = (const float*)d_in[6];
    const float* Wo = (const float*)d_in[7];
    const float* bo = (const float*)d_in[8];
    const float* Wc = (const float*)d_in[9];
    const float* bc = (const float*)d_in[10];
    float* out = (float*)d_out;

    char* p = (char*)d_ws;
    unsigned short* Wt   = (unsigned short*)p;  p += (size_t)1280 * 256 * 2;      // 640 KB
    float* bcat          = (float*)p;           p += (size_t)1280 * 4;            // 5 KB
    unsigned short* Qw   = (unsigned short*)p;  p += (size_t)32 * 2048 * 32 * 2;  // 4 MB
    unsigned short* Kw   = (unsigned short*)p;  p += (size_t)32 * 2048 * 32 * 2;  // 4 MB
    unsigned short* Vtw  = (unsigned short*)p;  p += (size_t)32 * 32 * 2048 * 2;  // 4 MB
    unsigned short* ctx  = (unsigned short*)p;  p += (size_t)MTOT * DMODEL * 2;   // 4 MB
    unsigned short* Woct = (unsigned short*)p;  p += (size_t)256 * 256 * 2;       // 128 KB
    float* bocf          = (float*)p;           p += (size_t)256 * 4;             // 1 KB

    // prep: 80 transpose + 257 fold + 5 bias = 342 blocks
    prep_kernel<<<342, 256, 0, stream>>>(Wq, Wk, Wv, Wo, Wc,
                                         bq, bk, bv, bo, bc,
                                         Wt, bcat, Woct, bocf);
    // QKV projection (reads fp32 x directly)
    gemm_qkv<<<dim3(64, 12), 256, 0, stream>>>(x, Wt, bcat, Qw, Kw, Vtw);
    // attention (R8 structure: in-block half combine, bf16 ctx)
    attn_kernel<<<512, 512, 0, stream>>>(Qw, Kw, Vtw, ctx);
    // fused output+context projection + residual
    gemm_ctx<<<dim3(64, 4), 256, 0, stream>>>(ctx, Woct, bocf, x, out);
}

// Round 11
// 62.988 us; speedup vs baseline: 1.3431x; 1.0774x over previous
//
#include <hip/hip_runtime.h>

// Problem constants
#define DMODEL 256
#define HEADS 8
#define DHEAD 32
#define NSEQ 2048
#define BATCH 4
#define MTOT (BATCH*NSEQ)   // 8192

typedef __bf16 bf16x8 __attribute__((ext_vector_type(8)));
typedef float f32x4 __attribute__((ext_vector_type(4)));

// scale * log2(e): softmax_e(s/sqrt(32)) == softmax_2(s * CS)
#define CS 0.25507282111989365f

__device__ __forceinline__ unsigned short f2bf(float f) {
    union { float f; unsigned int u; } v; v.f = f;
    unsigned int u = v.u;
    unsigned int r = u + 0x7FFFu + ((u >> 16) & 1u);   // RNE
    return (unsigned short)(r >> 16);
}

__device__ __forceinline__ unsigned pkbf(float a, float b) {
    union { __bf16 h[2]; unsigned u; } t;
    t.h[0] = (__bf16)a; t.h[1] = (__bf16)b;
    return t.u;
}

__device__ __forceinline__ f32x4 mfma16(bf16x8 a, bf16x8 b, f32x4 c) {
    return __builtin_amdgcn_mfma_f32_16x16x32_bf16(a, b, c, 0, 0, 0);
}

#define GLD16(g, l) __builtin_amdgcn_global_load_lds( \
    (const __attribute__((address_space(1))) unsigned int*)(g), \
    (__attribute__((address_space(3))) unsigned int*)(l), 16, 0, 0)

// ---------------------------------------------------------------------------
// prep (2390 blocks):
//  blocks 0..256    : Woc = Wo@Wc fold (row 256 = boc = bo@Wc + bc) [long pole]
//  blocks 257..2304 : x -> bf16 (coalesced float4 -> ushort4)
//  blocks 2305..2384: tiled-coalesced weight transpose -> Wt[n][k] bf16
//  blocks 2385..2389: bias concat
// ---------------------------------------------------------------------------
__global__ __launch_bounds__(256) void prep_kernel(
    const float* __restrict__ x,
    const float* __restrict__ Wq, const float* __restrict__ Wk,
    const float* __restrict__ Wv, const float* __restrict__ Wo,
    const float* __restrict__ Wc,
    const float* __restrict__ bq, const float* __restrict__ bk,
    const float* __restrict__ bv, const float* __restrict__ bo,
    const float* __restrict__ bc,
    unsigned short* __restrict__ xbf,   // [8192][256]
    unsigned short* __restrict__ Wt,    // [1280][256]
    float* __restrict__ bcat,           // [1280]
    unsigned short* __restrict__ Woct,  // [256][256] = Woc^T bf16
    float* __restrict__ bocf)           // [256]
{
    const int tid = threadIdx.x;
    if (blockIdx.x < 257) {             // Woc / boc fold
        int k = blockIdx.x;             // 0..256
        int n = tid;                    // 0..255
        const float* arow = (k < 256) ? (Wo + k * 256) : bo;
        float a0 = 0.f, a1 = 0.f, a2 = 0.f, a3 = 0.f;
#pragma unroll 4
        for (int j = 0; j < 256; j += 4) {
            a0 = fmaf(arow[j],     Wc[j * 256 + n],       a0);
            a1 = fmaf(arow[j + 1], Wc[(j + 1) * 256 + n], a1);
            a2 = fmaf(arow[j + 2], Wc[(j + 2) * 256 + n], a2);
            a3 = fmaf(arow[j + 3], Wc[(j + 3) * 256 + n], a3);
        }
        float acc = (a0 + a1) + (a2 + a3);
        if (k < 256) Woct[n * 256 + k] = f2bf(acc);
        else         bocf[n] = acc + bc[n];
        return;
    }
    if (blockIdx.x < 2305) {            // x -> bf16
        int idx = (blockIdx.x - 257) * 256 + tid;     // < 524288
        float4 v = reinterpret_cast<const float4*>(x)[idx];
        ushort4 o;
        o.x = f2bf(v.x); o.y = f2bf(v.y); o.z = f2bf(v.z); o.w = f2bf(v.w);
        reinterpret_cast<ushort4*>(xbf)[idx] = o;
        return;
    }
    if (blockIdx.x < 2385) {            // transpose: 64n x 64k tile
        __shared__ unsigned short Lt[64 * 72];
        const int bb = blockIdx.x - 2305;
        const int wid = tid >> 6, lane = tid & 63;
        const int n0 = (bb >> 2) * 64, k0 = (bb & 3) * 64;
        const float* Wsrc; int col0;
        if (n0 < 256)       { Wsrc = Wq; col0 = n0; }
        else if (n0 < 512)  { Wsrc = Wk; col0 = n0 - 256; }
        else if (n0 < 768)  { Wsrc = Wv; col0 = n0 - 512; }
        else if (n0 < 1024) { Wsrc = Wo; col0 = n0 - 768; }
        else                { Wsrc = Wc; col0 = n0 - 1024; }
#pragma unroll
        for (int r = 0; r < 16; ++r) {
            int k = k0 + wid * 16 + r;
            Lt[lane * 72 + wid * 16 + r] = f2bf(Wsrc[k * 256 + col0 + lane]);
        }
        __syncthreads();
#pragma unroll
        for (int c = tid; c < 512; c += 256) {
            int row = c >> 3, seg = c & 7;
            *reinterpret_cast<bf16x8*>(Wt + (n0 + row) * 256 + k0 + seg * 8) =
                *reinterpret_cast<const bf16x8*>(Lt + row * 72 + seg * 8);
        }
        return;
    }
    int t = (blockIdx.x - 2385) * 256 + tid;   // bias concat
    if (t < 1280) {
        float v;
        if (t < 256)       v = bq[t];
        else if (t < 512)  v = bk[t - 256];
        else if (t < 768)  v = bv[t - 512];
        else if (t < 1024) v = bo[t - 768];
        else               v = bc[t - 1024];
        bcat[t] = v;
    }
}

// ---------------------------------------------------------------------------
// gemm_qkv: A = xbf (bf16, narrow re-read stream). Wt staged in LDS
// (XOR-swizzled via pre-swizzled global_load_lds source). 32x64 per wave.
// LDS-bounce epilogue (all global stores b128):
//   type 0/1 (Q/K): [128 m][72]; Q pre-scaled by CS. type 2 (V): [64 gc][136].
// ---------------------------------------------------------------------------
__global__ __launch_bounds__(256) void gemm_qkv(
    const unsigned short* __restrict__ A,
    const unsigned short* __restrict__ Wt,
    const float* __restrict__ bias,
    unsigned short* __restrict__ outQ,
    unsigned short* __restrict__ outK,
    unsigned short* __restrict__ outVt)
{
    __shared__ __align__(16) unsigned short Bl[64 * 256];   // 32 KB
    const int tid = threadIdx.x;
    const int wid = tid >> 6;
    const int lane = tid & 63;
    const int lo = lane & 15, hi = lane >> 4;
    const int m0 = blockIdx.x * 128 + wid * 32;
    const int n0 = blockIdx.y * 64;

#pragma unroll
    for (int j = 0; j < 8; ++j) {
        int chunkbase = (j * 4 + wid) * 64;
        int chunk = chunkbase + lane;
        int row = chunk >> 5, Jp = chunk & 31;
        int J = (Jp & 24) | ((Jp ^ row) & 7);
        GLD16(Wt + (n0 + row) * 256 + J * 8, Bl + chunkbase * 8);
    }
    asm volatile("s_waitcnt vmcnt(0)" ::: "memory");
    __syncthreads();

    const unsigned short* arow0 = A + (m0 + lo) * 256 + hi * 8;
    f32x4 acc[2][4] = {};
#pragma unroll
    for (int s = 0; s < 8; ++s) {
        bf16x8 a0 = *reinterpret_cast<const bf16x8*>(arow0 + s * 32);
        bf16x8 a1 = *reinterpret_cast<const bf16x8*>(arow0 + 16 * 256 + s * 32);
        int Jp = ((s >> 1) << 3) | ((((s & 1) << 2) + hi) ^ (lo & 7));
#pragma unroll
        for (int n = 0; n < 4; ++n) {
            bf16x8 b = *reinterpret_cast<const bf16x8*>(
                Bl + (n * 16 + lo) * 256 + Jp * 8);
            acc[0][n] = mfma16(a0, b, acc[0][n]);
            acc[1][n] = mfma16(a1, b, acc[1][n]);
        }
    }

    // LDS-bounce epilogue
    const int type = blockIdx.y >> 2;     // 0:Q 1:K 2:V
    const int m0b = blockIdx.x * 128;
    unsigned short* Lb = Bl;
    __syncthreads();
    if (type < 2) {                       // [128][72]
#pragma unroll
        for (int mf = 0; mf < 2; ++mf)
#pragma unroll
        for (int n = 0; n < 4; ++n) {
            float bs = bias[n0 + n * 16 + lo];
#pragma unroll
            for (int i = 0; i < 4; ++i) {
                float val = acc[mf][n][i] + bs;
                if (type == 0) val *= CS;
                Lb[(wid * 32 + mf * 16 + hi * 4 + i) * 72 + n * 16 + lo] = f2bf(val);
            }
        }
    } else {                              // transposed [64][136]
#pragma unroll
        for (int mf = 0; mf < 2; ++mf)
#pragma unroll
        for (int n = 0; n < 4; ++n) {
            float bs = bias[n0 + n * 16 + lo];
            uint2 pk;
            pk.x = pkbf(acc[mf][n][0] + bs, acc[mf][n][1] + bs);
            pk.y = pkbf(acc[mf][n][2] + bs, acc[mf][n][3] + bs);
            *reinterpret_cast<uint2*>(
                Lb + (n * 16 + lo) * 136 + wid * 32 + mf * 16 + hi * 4) = pk;
        }
    }
    __syncthreads();
    if (type < 2) {
        unsigned short* outP = (type == 0) ? outQ : outK;
#pragma unroll
        for (int r = 0; r < 4; ++r) {
            int cid = r * 256 + tid;
            int m_l = cid >> 3, seg = cid & 7;
            bf16x8 chunk = *reinterpret_cast<const bf16x8*>(Lb + m_l * 72 + seg * 8);
            int m = m0b + m_l, gc = n0 + seg * 8;
            int b = m >> 11, nn = m & 2047, hh = (gc >> 5) & 7, dh = gc & 31;
            *reinterpret_cast<bf16x8*>(
                outP + (((b * 8) + hh) * 2048 + nn) * 32 + dh) = chunk;
        }
    } else {
#pragma unroll
        for (int r = 0; r < 4; ++r) {
            int cid = r * 256 + tid;
            int gcl = cid >> 4, seg = cid & 15;
            bf16x8 chunk = *reinterpret_cast<const bf16x8*>(Lb + gcl * 136 + seg * 8);
            int gc = n0 + gcl, m = m0b + seg * 8;
            int b = m >> 11, nn = m & 2047, hh = (gc >> 5) & 7, dh = gc & 31;
            *reinterpret_cast<bf16x8*>(
                outVt + (((b * 8) + hh) * 32 + dh) * 2048 + nn) = chunk;
        }
    }
}

// ---------------------------------------------------------------------------
// Flash attention v7: 512 blocks x 256 threads (4 waves x 32 q = 128 q/block),
// each block walks ALL 2048 keys (16 x 128-key tiles, double-buffered 32 KB
// LDS) -> 4 independent barrier domains per CU, barrier width 4 waves, NO
// combine phase. No-max softmax; P in-register (permlane); denom via
// ones-MFMA; bf16 ctx written directly.
// ---------------------------------------------------------------------------
__global__ __launch_bounds__(256, 4) void attn_kernel(
    const unsigned short* __restrict__ Q,    // [32][2048][32] bf16 (pre-scaled)
    const unsigned short* __restrict__ K,    // [32][2048][32] bf16
    const unsigned short* __restrict__ Vt,   // [32][32][2048] bf16
    unsigned short* __restrict__ ctx)        // [8192][256] bf16 (heads merged)
{
    __shared__ __align__(16) char smem[32768];   // K: [2][8KB] @0, V: [2][8KB] @16384

    const int tid = threadIdx.x;
    const int wid = tid >> 6;          // q sub-tile 0..3
    const int lane = tid & 63;
    const int lo = lane & 15, hi = lane >> 4;

    // XCD swizzle: bid = 8*(qt + 16*g) + r ; bh = g*8+r
    const int bid = blockIdx.x;
    const int bh = ((bid >> 7) << 3) | (bid & 7);
    const int qt = (bid >> 3) & 15;
    const int q0 = qt * 128 + wid * 32;

    const unsigned short* Qb = Q + bh * (NSEQ * 32);
    const unsigned short* Kb = K + bh * (NSEQ * 32);
    const unsigned short* Vb = Vt + bh * (32 * NSEQ);

    bf16x8 qfA = *reinterpret_cast<const bf16x8*>(Qb + (q0 + lo) * 32 + hi * 8);
    bf16x8 qfB = *reinterpret_cast<const bf16x8*>(Qb + (q0 + 16 + lo) * 32 + hi * 8);

    // staging: 256 threads stage 8 KB K + 8 KB V per 128-key tile (4 GLD16)
    const int lt = tid;
    const unsigned short* ksrc0 = Kb + (2 * (lt >> 3) + ((lt >> 2) & 1)) * 32
                                     + ((lt & 3) ^ ((lt >> 3) & 3)) * 8;
    const unsigned short* ksrc1 = ksrc0 + 64 * 32;
    const unsigned short* vsrc0 = Vb + (lt >> 3) * NSEQ
                                     + ((lt & 7) ^ ((lt >> 3) & 7)) * 8;
    const unsigned short* vsrc1 = vsrc0 + 64;
    char* kdst = smem + lt * 16;
    char* vdst = smem + 16384 + lt * 16;

    f32x4 o0A = {}, o1A = {}, odA = {};
    f32x4 o0B = {}, o1B = {}, odB = {};
    const f32x4 z = {};
    const int prs = lo & 7;
    const int kxor = (hi ^ ((lo >> 1) & 3)) * 8;

    union { unsigned u[4]; bf16x8 v; } ones;
    ones.u[0] = 0x3F803F80u; ones.u[1] = 0x3F803F80u;
    ones.u[2] = 0x3F803F80u; ones.u[3] = 0x3F803F80u;

#define STAGE_T(tt, buf) do { \
    GLD16(ksrc0 + (tt) * 4096, kdst + (buf) * 8192); \
    GLD16(ksrc1 + (tt) * 4096, kdst + (buf) * 8192 + 4096); \
    GLD16(vsrc0 + (tt) * 128,  vdst + (buf) * 8192); \
    GLD16(vsrc1 + (tt) * 128,  vdst + (buf) * 8192 + 4096); \
} while (0)

    STAGE_T(0, 0);
    asm volatile("s_waitcnt vmcnt(0)" ::: "memory");
    __builtin_amdgcn_s_barrier();
    __builtin_amdgcn_sched_barrier(0);

    int cur = 0;
    for (int t = 0; t < 16; ++t) {
        if (t < 15) STAGE_T(t + 1, cur ^ 1);
        const unsigned short* Kc = (const unsigned short*)(smem + cur * 8192);
        const unsigned short* Vc = (const unsigned short*)(smem + 16384 + cur * 8192);

        __builtin_amdgcn_s_setprio(1);
#pragma unroll
        for (int h2 = 0; h2 < 2; ++h2) {     // 64-key sub-tiles
            const unsigned short* Kh = Kc + h2 * 2048;
            const unsigned short* Vh = Vc + h2 * 2048;
            f32x4 sA[4], sB[4];
#pragma unroll
            for (int c = 0; c < 4; ++c) {
                bf16x8 kf = *reinterpret_cast<const bf16x8*>(
                    Kh + (c * 16 + lo) * 32 + kxor);
                sA[c] = mfma16(kf, qfA, z);
                sB[c] = mfma16(kf, qfB, z);
            }
#pragma unroll
            for (int kk = 0; kk < 2; ++kk) {
                unsigned uA = pkbf(__builtin_amdgcn_exp2f(sA[2 * kk][0]),
                                   __builtin_amdgcn_exp2f(sA[2 * kk][1]));
                unsigned uB = pkbf(__builtin_amdgcn_exp2f(sA[2 * kk][2]),
                                   __builtin_amdgcn_exp2f(sA[2 * kk][3]));
                unsigned uC = pkbf(__builtin_amdgcn_exp2f(sA[2 * kk + 1][0]),
                                   __builtin_amdgcn_exp2f(sA[2 * kk + 1][1]));
                unsigned uD = pkbf(__builtin_amdgcn_exp2f(sA[2 * kk + 1][2]),
                                   __builtin_amdgcn_exp2f(sA[2 * kk + 1][3]));
                auto r1 = __builtin_amdgcn_permlane32_swap(uA, uC, false, false);
                auto r2 = __builtin_amdgcn_permlane16_swap(r1[0], r1[1], false, false);
                auto r3 = __builtin_amdgcn_permlane32_swap(uB, uD, false, false);
                auto r4 = __builtin_amdgcn_permlane16_swap(r3[0], r3[1], false, false);
                union { unsigned u[4]; bf16x8 v; } pbA;
                pbA.u[0] = r2[0]; pbA.u[1] = r4[0]; pbA.u[2] = r2[1]; pbA.u[3] = r4[1];

                unsigned wA = pkbf(__builtin_amdgcn_exp2f(sB[2 * kk][0]),
                                   __builtin_amdgcn_exp2f(sB[2 * kk][1]));
                unsigned wB = pkbf(__builtin_amdgcn_exp2f(sB[2 * kk][2]),
                                   __builtin_amdgcn_exp2f(sB[2 * kk][3]));
                unsigned wC = pkbf(__builtin_amdgcn_exp2f(sB[2 * kk + 1][0]),
                                   __builtin_amdgcn_exp2f(sB[2 * kk + 1][1]));
                unsigned wD = pkbf(__builtin_amdgcn_exp2f(sB[2 * kk + 1][2]),
                                   __builtin_amdgcn_exp2f(sB[2 * kk + 1][3]));
                auto t1 = __builtin_amdgcn_permlane32_swap(wA, wC, false, false);
                auto t2 = __builtin_amdgcn_permlane16_swap(t1[0], t1[1], false, false);
                auto t3 = __builtin_amdgcn_permlane32_swap(wB, wD, false, false);
                auto t4 = __builtin_amdgcn_permlane16_swap(t3[0], t3[1], false, false);
                union { unsigned u[4]; bf16x8 v; } pbB;
                pbB.u[0] = t2[0]; pbB.u[1] = t4[0]; pbB.u[2] = t2[1]; pbB.u[3] = t4[1];

                int sw = ((4 * kk + hi) ^ prs) * 8;
                bf16x8 a0 = *reinterpret_cast<const bf16x8*>(Vh + lo * 64 + sw);
                bf16x8 a1 = *reinterpret_cast<const bf16x8*>(Vh + (16 + lo) * 64 + sw);
                o0A = mfma16(a0, pbA.v, o0A);
                o1A = mfma16(a1, pbA.v, o1A);
                odA = mfma16(ones.v, pbA.v, odA);
                o0B = mfma16(a0, pbB.v, o0B);
                o1B = mfma16(a1, pbB.v, o1B);
                odB = mfma16(ones.v, pbB.v, odB);
            }
        }
        __builtin_amdgcn_s_setprio(0);

        if (t < 15) {
            asm volatile("s_waitcnt vmcnt(0)" ::: "memory");
            __builtin_amdgcn_s_barrier();
            __builtin_amdgcn_sched_barrier(0);
            cur ^= 1;
        }
    }

    // epilogue: no combine — full softmax owned by this wave
    float invA = 1.0f / odA[0];
    float invB = 1.0f / odB[0];
    const int b = bh >> 3, h = bh & 7;
    unsigned short* dstA = ctx + (size_t)((b * 2048 + q0 + lo)) * 256 + h * 32;
    unsigned short* dstB = dstA + 16 * 256;
    ushort4 w0, w1;
    w0.x = f2bf(o0A[0] * invA); w0.y = f2bf(o0A[1] * invA);
    w0.z = f2bf(o0A[2] * invA); w0.w = f2bf(o0A[3] * invA);
    w1.x = f2bf(o1A[0] * invA); w1.y = f2bf(o1A[1] * invA);
    w1.z = f2bf(o1A[2] * invA); w1.w = f2bf(o1A[3] * invA);
    *reinterpret_cast<ushort4*>(dstA + hi * 4)      = w0;
    *reinterpret_cast<ushort4*>(dstA + 16 + hi * 4) = w1;
    w0.x = f2bf(o0B[0] * invB); w0.y = f2bf(o0B[1] * invB);
    w0.z = f2bf(o0B[2] * invB); w0.w = f2bf(o0B[3] * invB);
    w1.x = f2bf(o1B[0] * invB); w1.y = f2bf(o1B[1] * invB);
    w1.z = f2bf(o1B[2] * invB); w1.w = f2bf(o1B[3] * invB);
    *reinterpret_cast<ushort4*>(dstB + hi * 4)      = w0;
    *reinterpret_cast<ushort4*>(dstB + 16 + hi * 4) = w1;
#undef STAGE_T
}

// ---------------------------------------------------------------------------
// gemm_ctx: out = x + ctx @ Woc + boc. A = ctx bf16 direct; B = Woct staged
// in LDS (swizzled). 32 rows x 64 cols / wave.
// ---------------------------------------------------------------------------
__global__ __launch_bounds__(256) void gemm_ctx(
    const unsigned short* __restrict__ A,
    const unsigned short* __restrict__ Wt,
    const float* __restrict__ boc,
    const float* __restrict__ xres,
    float* __restrict__ outF)
{
    __shared__ __align__(16) unsigned short Bl[64 * 256];   // 32 KB
    const int tid = threadIdx.x;
    const int wid = tid >> 6;
    const int lane = tid & 63;
    const int lo = lane & 15, hi = lane >> 4;
    const int m0 = blockIdx.x * 128 + wid * 32;
    const int n0 = blockIdx.y * 64;

#pragma unroll
    for (int j = 0; j < 8; ++j) {
        int chunkbase = (j * 4 + wid) * 64;
        int chunk = chunkbase + lane;
        int row = chunk >> 5, Jp = chunk & 31;
        int J = (Jp & 24) | ((Jp ^ row) & 7);
        GLD16(Wt + (n0 + row) * 256 + J * 8, Bl + chunkbase * 8);
    }
    asm volatile("s_waitcnt vmcnt(0)" ::: "memory");
    __syncthreads();

    const unsigned short* arow0 = A + (m0 + lo) * 256 + hi * 8;
    f32x4 acc[2][4] = {};
#pragma unroll
    for (int s = 0; s < 8; ++s) {
        bf16x8 a0 = *reinterpret_cast<const bf16x8*>(arow0 + s * 32);
        bf16x8 a1 = *reinterpret_cast<const bf16x8*>(arow0 + 16 * 256 + s * 32);
        int Jp = ((s >> 1) << 3) | ((((s & 1) << 2) + hi) ^ (lo & 7));
#pragma unroll
        for (int n = 0; n < 4; ++n) {
            bf16x8 b = *reinterpret_cast<const bf16x8*>(
                Bl + (n * 16 + lo) * 256 + Jp * 8);
            acc[0][n] = mfma16(a0, b, acc[0][n]);
            acc[1][n] = mfma16(a1, b, acc[1][n]);
        }
    }
#pragma unroll
    for (int mf = 0; mf < 2; ++mf) {
        const int row_base = m0 + mf * 16 + hi * 4;
#pragma unroll
        for (int n = 0; n < 4; ++n) {
            int gc = n0 + n * 16 + lo;
            float bs = boc[gc];
#pragma unroll
            for (int i = 0; i < 4; ++i)
                outF[(row_base + i) * 256 + gc] =
                    xres[(row_base + i) * 256 + gc] + acc[mf][n][i] + bs;
        }
    }
}

// ---------------------------------------------------------------------------
extern "C" void kernel_launch(void* const* d_in, const int* in_sizes, int n_in,
                              void* d_out, int out_size, void* d_ws, size_t ws_size,
                              hipStream_t stream) {
    const float* x  = (const float*)d_in[0];
    const float* Wq = (const float*)d_in[1];
    const float* bq = (const float*)d_in[2];
    const float* Wk = (const float*)d_in[3];
    const float* bk = (const float*)d_in[4];
    const float* Wv = (const float*)d_in[5];
    const float* bv = (const float*)d_in[6];
    const float* Wo = (const float*)d_in[7];
    const float* bo = (const float*)d_in[8];
    const float* Wc = (const float*)d_in[9];
    const float* bc = (const float*)d_in[10];
    float* out = (float*)d_out;

    char* p = (char*)d_ws;
    unsigned short* xbf  = (unsigned short*)p;  p += (size_t)MTOT * DMODEL * 2;   // 4 MB
    unsigned short* Wt   = (unsigned short*)p;  p += (size_t)1280 * 256 * 2;      // 640 KB
    float* bcat          = (float*)p;           p += (size_t)1280 * 4;            // 5 KB
    unsigned short* Qw   = (unsigned short*)p;  p += (size_t)32 * 2048 * 32 * 2;  // 4 MB
    unsigned short* Kw   = (unsigned short*)p;  p += (size_t)32 * 2048 * 32 * 2;  // 4 MB
    unsigned short* Vtw  = (unsigned short*)p;  p += (size_t)32 * 32 * 2048 * 2;  // 4 MB
    unsigned short* ctx  = (unsigned short*)p;  p += (size_t)MTOT * DMODEL * 2;   // 4 MB
    unsigned short* Woct = (unsigned short*)p;  p += (size_t)256 * 256 * 2;       // 128 KB
    float* bocf          = (float*)p;           p += (size_t)256 * 4;             // 1 KB

    // prep: 257 fold + 2048 xconv + 80 transpose + 5 bias = 2390 blocks
    prep_kernel<<<2390, 256, 0, stream>>>(x, Wq, Wk, Wv, Wo, Wc,
                                          bq, bk, bv, bo, bc,
                                          xbf, Wt, bcat, Woct, bocf);
    // QKV projection (bf16 A stream)
    gemm_qkv<<<dim3(64, 12), 256, 0, stream>>>(xbf, Wt, bcat, Qw, Kw, Vtw);
    // attention (4 barrier domains/CU, no combine)
    attn_kernel<<<512, 256, 0, stream>>>(Qw, Kw, Vtw, ctx);
    // fused output+context projection + residual
    gemm_ctx<<<dim3(64, 4), 256, 0, stream>>>(ctx, Woct, bocf, x, out);
}